// Round 6
// baseline (296.282 us; speedup 1.0000x reference)
//
#include <hip/hip_runtime.h>
#include <float.h>
#include <math.h>

#define BATCH 8
#define NPTS 4096
#define KNN 10
#define BN (BATCH * NPTS)          // 32768 points per cloud
#define NCLOUD (2 * BATCH)         // 16 clouds (pred+gt) x batch
#define PAD 16                     // sentinel guard band each side
#define STRIDE (NPTS + 2 * PAD)

__device__ float4 g_spts[NCLOUD * STRIDE];  // x-sorted + guards (x,y,z,|p|^2)
__device__ int    g_perm[NCLOUD * NPTS];    // sorted pos -> original idx
__device__ float4 g_nrm[2 * BN];            // normals in original order

__device__ inline float med3f(float x, float a, float b) {
    return __builtin_amdgcn_fmed3f(x, a, b);
}

// branchless sorted insert of key into ascending k[0..9] (drop largest)
#define INSERT(karr, key)                                              \
    do {                                                               \
        _Pragma("unroll")                                              \
        for (int _j = KNN - 1; _j >= 1; --_j)                          \
            karr[_j] = med3f((key), karr[_j - 1], karr[_j]);           \
        karr[0] = fminf((key), karr[0]);                               \
    } while (0)

// distance + pack(sorted idx 12b) + insert; guards give d~1e30 (finite,
// never inserted over the 1e28 init, no NaN in med3)
#define PROC1(_p, _gi)                                                 \
    do {                                                               \
        float _d = fmaf((_p).z, a0z, fmaf((_p).y, a0y, fmaf((_p).x, a0x, (_p).w))); \
        float _k = __uint_as_float((__float_as_uint(_d) & 0xFFFFF000u) | ((unsigned)(_gi) & 0xFFFu)); \
        INSERT(kq, _k);                                                \
    } while (0)

#define PROC8(P, _ib)                                                  \
    do {                                                               \
        PROC1(P##0, (_ib) + 0); PROC1(P##1, (_ib) + 1);                \
        PROC1(P##2, (_ib) + 2); PROC1(P##3, (_ib) + 3);                \
        PROC1(P##4, (_ib) + 4); PROC1(P##5, (_ib) + 5);                \
        PROC1(P##6, (_ib) + 6); PROC1(P##7, (_ib) + 7);                \
    } while (0)

#define LOADG(P, _i)                                                   \
    do {                                                               \
        P##0 = cp[(_i) + 0]; P##1 = cp[(_i) + 1];                      \
        P##2 = cp[(_i) + 2]; P##3 = cp[(_i) + 3];                      \
        P##4 = cp[(_i) + 4]; P##5 = cp[(_i) + 5];                      \
        P##6 = cp[(_i) + 6]; P##7 = cp[(_i) + 7];                      \
    } while (0)

// prune threshold ~ d10^2 (+ margin covering 12-bit key truncation);
// keys init 1e28 so thr stays < guard dx^2 = 1e30 (always terminates)
#define RETHR() (kq[KNN - 1] + qw2 + fmaf(fabsf(kq[KNN - 1]), 2e-3f, 1e-4f))

// Eigenvector of smallest eigenvalue of symmetric 3x3
__device__ inline void smallest_eigvec(float a00, float a01, float a02,
                                       float a11, float a12, float a22,
                                       float& vx, float& vy, float& vz) {
    float p1 = a01 * a01 + a02 * a02 + a12 * a12;
    float q = (a00 + a11 + a22) * (1.0f / 3.0f);
    float b00 = a00 - q, b11 = a11 - q, b22 = a22 - q;
    float p2 = b00 * b00 + b11 * b11 + b22 * b22 + 2.0f * p1;
    float p = sqrtf(p2 * (1.0f / 6.0f));
    if (p < 1e-20f) { vx = 1.0f; vy = 0.0f; vz = 0.0f; return; }
    float ip = 1.0f / p;
    float c00 = b00 * ip, c01 = a01 * ip, c02 = a02 * ip;
    float c11 = b11 * ip, c12 = a12 * ip, c22 = b22 * ip;
    float detB = c00 * (c11 * c22 - c12 * c12)
               - c01 * (c01 * c22 - c12 * c02)
               + c02 * (c01 * c12 - c11 * c02);
    float r = 0.5f * detB;
    r = fminf(1.0f, fmaxf(-1.0f, r));
    float phi = acosf(r) * (1.0f / 3.0f);
    float lmin = q + 2.0f * p * cosf(phi + 2.0943951023931953f);

    float m00 = a00 - lmin, m11 = a11 - lmin, m22 = a22 - lmin;
    float r0x = m00, r0y = a01, r0z = a02;
    float r1x = a01, r1y = m11, r1z = a12;
    float r2x = a02, r2y = a12, r2z = m22;
    float c0x = r0y * r1z - r0z * r1y, c0y = r0z * r1x - r0x * r1z, c0z = r0x * r1y - r0y * r1x;
    float c1x = r0y * r2z - r0z * r2y, c1y = r0z * r2x - r0x * r2z, c1z = r0x * r2y - r0y * r2x;
    float c2x = r1y * r2z - r1z * r2y, c2y = r1z * r2x - r1x * r2z, c2z = r1x * r2y - r1y * r2x;
    float n0 = c0x * c0x + c0y * c0y + c0z * c0z;
    float n1 = c1x * c1x + c1y * c1y + c1z * c1z;
    float n2 = c2x * c2x + c2y * c2y + c2z * c2z;
    float bx = c0x, by = c0y, bz = c0z, bnm = n0;
    if (n1 > bnm) { bx = c1x; by = c1y; bz = c1z; bnm = n1; }
    if (n2 > bnm) { bx = c2x; by = c2y; bz = c2z; bnm = n2; }
    if (bnm < 1e-30f) { vx = 1.0f; vy = 0.0f; vz = 0.0f; return; }
    float inv = rsqrtf(bnm);
    vx = bx * inv; vy = by * inv; vz = bz * inv;
}

__global__ void zero_out_kernel(float* __restrict__ out) {
    if (threadIdx.x == 0) out[0] = 0.0f;
}

// one block per cloud: in-LDS bitonic sort of 4096 (x, idx) pairs, then
// emit padded sorted float4 (x,y,z,|p|^2) + guard sentinels + permutation
__global__ __launch_bounds__(1024) void sort_clouds(
    const float* __restrict__ pred, const float* __restrict__ gt) {
    __shared__ float skey[NPTS];
    __shared__ int   sidx[NPTS];
    const int c = blockIdx.x;
    const float* __restrict__ base =
        (c >= BATCH) ? (gt + (c - BATCH) * 3 * NPTS) : (pred + c * 3 * NPTS);
    const int tid = threadIdx.x;

    for (int i = tid; i < NPTS; i += 1024) { skey[i] = base[i]; sidx[i] = i; }

    for (int k = 2; k <= NPTS; k <<= 1) {
        for (int j = k >> 1; j > 0; j >>= 1) {
            __syncthreads();
            for (int t = tid; t < NPTS / 2; t += 1024) {
                int i = ((t / j) * 2 * j) + (t % j);
                int p = i + j;
                bool up = ((i & k) == 0);
                float a = skey[i], bb = skey[p];
                bool sw = up ? (a > bb) : (a < bb);
                if (sw) {
                    skey[i] = bb; skey[p] = a;
                    int ia = sidx[i]; sidx[i] = sidx[p]; sidx[p] = ia;
                }
            }
        }
    }
    __syncthreads();

    const int cb = c * STRIDE;
    for (int i = tid; i < NPTS; i += 1024) {
        int idx = sidx[i];
        float x = skey[i];
        float y = base[NPTS + idx];
        float z = base[2 * NPTS + idx];
        g_spts[cb + PAD + i] = make_float4(x, y, z, fmaf(x, x, fmaf(y, y, z * z)));
        g_perm[c * NPTS + i] = idx;
    }
    if (tid < PAD) {   // finite sentinels: huge dx (stops expansion), huge d (never inserted)
        g_spts[cb + tid]              = make_float4(-1e15f, 0.f, 0.f, 1e30f);
        g_spts[cb + PAD + NPTS + tid] = make_float4( 1e15f, 0.f, 0.f, 1e30f);
    }
}

// One block = 64 consecutive x-sorted queries, 2 waves: wave 0 expands LEFT,
// wave 1 RIGHT — PER LANE (own query, own window, own break; no __all
// lock-step, no broadcast reads). Candidates from global (L2-hot, coalesced:
// consecutive lanes read consecutive float4). A/B register double-buffer
// prefetches next chunk under current chunk's ~120 VALU ops; guard bands
// absorb prefetch overshoot. Grid (group, cloud): consecutive blocks are
// different groups -> mixed window sizes per CU -> load balance.
__global__ __launch_bounds__(128) void knn_window() {
    __shared__ float keybuf[64][KNN + 1];

    const int bx = blockIdx.x;            // query group 0..63
    const int c  = blockIdx.y;            // cloud 0..15
    const int lane = threadIdx.x & 63;
    const int w    = threadIdx.x >> 6;    // 0 = left, 1 = right
    const float4* __restrict__ cp = g_spts + c * STRIDE + PAD;  // cp[i], i in [-PAD, NPTS+PAD)
    const int s = bx * 64 + lane;         // my sorted query position

    const float4 qp = cp[s];
    const float qx = qp.x, qw2 = qp.w;
    const float a0x = -2.0f * qp.x, a0y = -2.0f * qp.y, a0z = -2.0f * qp.z;

    float kq[KNN];
#pragma unroll
    for (int j = 0; j < KNN; ++j) kq[j] = 1e28f;

    float4 A0, A1, A2, A3, A4, A5, A6, A7;
    float4 B0, B1, B2, B3, B4, B5, B6, B7;

    if (w == 0) {
        // LEFT: chunks [i, i+7] walking down from s-8 (excludes self)
        int i = s - 8;
        LOADG(A, i);
        for (;;) {
            LOADG(B, i - 8);
            PROC8(A, i);
            float thr = RETHR();
            float dxe = qx - A0.x;
            if (dxe * dxe >= thr || i - 8 < -8) break;
            i -= 8;
            LOADG(A, i - 8);
            PROC8(B, i);
            thr = RETHR();
            dxe = qx - B0.x;
            if (dxe * dxe >= thr || i - 8 < -8) break;
            i -= 8;
        }
    } else {
        // RIGHT: chunks [i, i+7] walking up from s (includes self, d=0)
        int i = s;
        LOADG(A, i);
        for (;;) {
            LOADG(B, i + 8);
            PROC8(A, i);
            float thr = RETHR();
            float dxe = A7.x - qx;
            if (dxe * dxe >= thr || i + 8 > NPTS) break;
            i += 8;
            LOADG(A, i + 8);
            PROC8(B, i);
            thr = RETHR();
            dxe = B7.x - qx;
            if (dxe * dxe >= thr || i + 8 > NPTS) break;
            i += 8;
        }
    }

    // merge: left wave publishes, right wave folds in + finishes the query
    if (w == 0) {
#pragma unroll
        for (int j = 0; j < KNN; ++j) keybuf[lane][j] = kq[j];
    }
    __syncthreads();
    if (w == 1) {
#pragma unroll
        for (int j = 0; j < KNN; ++j) { float v = keybuf[lane][j]; INSERT(kq, v); }

        float sx = 0.f, sy = 0.f, sz = 0.f;
        float sxx = 0.f, sxy = 0.f, sxz = 0.f;
        float syy = 0.f, syz = 0.f, szz = 0.f;
#pragma unroll
        for (int j = 0; j < KNN; ++j) {
            int idx = (int)(__float_as_uint(kq[j]) & 0xFFFu);
            float4 nb = cp[idx];                  // L2-hot gather
            sx += nb.x; sy += nb.y; sz += nb.z;
            sxx = fmaf(nb.x, nb.x, sxx); sxy = fmaf(nb.x, nb.y, sxy); sxz = fmaf(nb.x, nb.z, sxz);
            syy = fmaf(nb.y, nb.y, syy); syz = fmaf(nb.y, nb.z, syz); szz = fmaf(nb.z, nb.z, szz);
        }
        const float iK = 1.0f / KNN;
        float mx = sx * iK, my = sy * iK, mz = sz * iK;
        float vx, vy, vz;
        smallest_eigvec(sxx * iK - mx * mx, sxy * iK - mx * my,
                        sxz * iK - mx * mz, syy * iK - my * my,
                        syz * iK - my * mz, szz * iK - mz * mz,
                        vx, vy, vz);
        const int cs = c >> 3, b = c & 7;
        const int oq = g_perm[c * NPTS + s];      // scatter to original order
        g_nrm[cs * BN + b * NPTS + oq] = make_float4(vx, vy, vz, 0.f);
    }
}

// loss over 32768 point pairs; one wave-sum atomic per 64 lanes
__global__ __launch_bounds__(256) void cos_loss_kernel(float* __restrict__ out) {
    const int i = blockIdx.x * 256 + threadIdx.x;     // grid sized exactly BN
    float4 p = g_nrm[i];
    float4 g = g_nrm[BN + i];
    float dot = p.x * g.x + p.y * g.y + p.z * g.z;
    float npn = sqrtf(p.x * p.x + p.y * p.y + p.z * p.z);
    float ngn = sqrtf(g.x * g.x + g.y * g.y + g.z * g.z);
    float acc = 1.0f - fabsf(dot / fmaxf(npn * ngn, 1e-8f));
    for (int off = 32; off > 0; off >>= 1) acc += __shfl_down(acc, off);
    if ((threadIdx.x & 63) == 0) atomicAdd(out, acc * (1.0f / (float)BN));
}

extern "C" void kernel_launch(void* const* d_in, const int* in_sizes, int n_in,
                              void* d_out, int out_size, void* d_ws, size_t ws_size,
                              hipStream_t stream) {
    const float* pred = (const float*)d_in[0];
    const float* gt = (const float*)d_in[1];
    float* out = (float*)d_out;

    zero_out_kernel<<<1, 64, 0, stream>>>(out);
    sort_clouds<<<dim3(NCLOUD), 1024, 0, stream>>>(pred, gt);
    knn_window<<<dim3(NPTS / 64, NCLOUD), 128, 0, stream>>>();
    cos_loss_kernel<<<dim3(BN / 256), 256, 0, stream>>>(out);
}